// Round 19
// baseline (325.101 us; speedup 1.0000x reference)
//
#include <hip/hip_runtime.h>
#include <math.h>

typedef __attribute__((ext_vector_type(8))) short bf16x8;
typedef __attribute__((ext_vector_type(4))) short bf16x4_t;
typedef __attribute__((ext_vector_type(4))) float f32x4;
typedef __attribute__((ext_vector_type(4))) unsigned int u32x4;

typedef const __attribute__((address_space(1))) unsigned int glb_u32;
typedef __attribute__((address_space(3))) unsigned int lds_u32;
#define GLOAD_LDS16(g, l) __builtin_amdgcn_global_load_lds( \
    (glb_u32*)(const void*)(g), (lds_u32*)(void*)(l), 16, 0, 0)

static __device__ __forceinline__ float4 ld4(const float* p) {
    return *reinterpret_cast<const float4*>(p);
}
static __device__ __forceinline__ unsigned short f2bf(float f) {
    unsigned int u = __float_as_uint(f);
    u += 0x7fffu + ((u >> 16) & 1u);
    return (unsigned short)(u >> 16);
}
// Raw v_exp_f32 (2^x), no libm conformance wrapper (R17: -18% on attn).
static __device__ __forceinline__ float fexp2(float x) {
    return __builtin_amdgcn_exp2f(x);
}
// tanh-form GELU via exp2 + rcp: gelu(x) ~= x * t/(t+1), t = 2^(x*(a*x^2+b)).
static __device__ __forceinline__ float gelu_f(float v) {
    float t = fexp2(v * fmaf(v * v, 0.1029430f, 2.3022172f));
    return v - v * __builtin_amdgcn_rcpf(t + 1.f);
}

// ---------------------------------------------------------------------------
// LayerNorm: 4 rows per block (4 waves), bf16 output.
// mode=1: in_row = r + 1 + r/3136 (patch rows of (2,3137,512)).
// ---------------------------------------------------------------------------
__global__ __launch_bounds__(256) void ln_kernel(
    const float* __restrict__ in, const float* __restrict__ g,
    const float* __restrict__ bta, unsigned short* __restrict__ out,
    int mode, int nrows)
{
    int r = blockIdx.x * 4 + (threadIdx.x >> 6);
    if (r >= nrows) return;
    int lane = threadIdx.x & 63;
    int in_r = mode ? (r + 1 + r / 3136) : r;
    const float* xp = in + (size_t)in_r * 512 + lane * 8;
    float4 v0 = ld4(xp), v1 = ld4(xp + 4);
    float s  = v0.x + v0.y + v0.z + v0.w + v1.x + v1.y + v1.z + v1.w;
    float sq = v0.x*v0.x + v0.y*v0.y + v0.z*v0.z + v0.w*v0.w
             + v1.x*v1.x + v1.y*v1.y + v1.z*v1.z + v1.w*v1.w;
    #pragma unroll
    for (int off = 32; off; off >>= 1) {
        s  += __shfl_xor(s, off);
        sq += __shfl_xor(sq, off);
    }
    float mean = s * (1.f / 512.f);
    float var  = fmaxf(sq * (1.f / 512.f) - mean * mean, 0.f);
    float rstd = rsqrtf(var + 1e-5f);
    float4 g0 = ld4(g + lane * 8),   g1 = ld4(g + lane * 8 + 4);
    float4 b0 = ld4(bta + lane * 8), b1 = ld4(bta + lane * 8 + 4);
    float o0 = (v0.x - mean) * rstd * g0.x + b0.x;
    float o1 = (v0.y - mean) * rstd * g0.y + b0.y;
    float o2 = (v0.z - mean) * rstd * g0.z + b0.z;
    float o3 = (v0.w - mean) * rstd * g0.w + b0.w;
    float o4 = (v1.x - mean) * rstd * g1.x + b1.x;
    float o5 = (v1.y - mean) * rstd * g1.y + b1.y;
    float o6 = (v1.z - mean) * rstd * g1.z + b1.z;
    float o7 = (v1.w - mean) * rstd * g1.w + b1.w;
    u32x4 pk;
    pk[0] = (unsigned int)f2bf(o0) | ((unsigned int)f2bf(o1) << 16);
    pk[1] = (unsigned int)f2bf(o2) | ((unsigned int)f2bf(o3) << 16);
    pk[2] = (unsigned int)f2bf(o4) | ((unsigned int)f2bf(o5) << 16);
    pk[3] = (unsigned int)f2bf(o6) | ((unsigned int)f2bf(o7) << 16);
    *(u32x4*)(out + (size_t)r * 512 + lane * 8) = pk;
}

// ---------------------------------------------------------------------------
// All six weight transposes in one launch. W[K][N] -> WT[N][K] bf16.
// ---------------------------------------------------------------------------
struct TransArgs {
    const float* src[6];
    unsigned short* dst[6];
    int N[6], K[6], off[6];
};

__global__ __launch_bounds__(256) void transpose_all(TransArgs a)
{
    __shared__ unsigned short tile[32][34];
    int t = blockIdx.x;
    int i = 0;
    #pragma unroll
    for (int j = 1; j < 6; ++j) if (t >= a.off[j]) i = j;
    int rel = t - a.off[i];
    int tx_n = a.N[i] >> 5;
    int bx = (rel % tx_n) * 32, by = (rel / tx_n) * 32;
    const float* W = a.src[i];
    unsigned short* WT = a.dst[i];
    int K = a.K[i], N = a.N[i];
    int tx = threadIdx.x & 31, ty = threadIdx.x >> 5;
    #pragma unroll
    for (int r = 0; r < 32; r += 8)
        tile[ty + r][tx] = f2bf(W[(size_t)(by + ty + r) * N + bx + tx]);
    __syncthreads();
    #pragma unroll
    for (int r = 0; r < 32; r += 8)
        WT[(size_t)(bx + ty + r) * K + by + tx] = tile[tx][ty + r];
}

// ---------------------------------------------------------------------------
// MFMA bf16 GEMM, DEPTH-deep pipelined global_load_lds (counted vmcnt, raw
// barriers). DEPTH=3: buf[cur]'s loads get ~2 K-steps to land (~400-500cy
// vs L2-hit ~200cy / HBM ~900cy). Grid: x = N-tiles (fastest), y = M-tiles.
// vt_out: cols >= vtColBase go to [b][col-vtColBase][token] layout.
// ---------------------------------------------------------------------------
template<int BM, int BN, int SUB, int DEPTH, int OUT_BF16>
__global__ __launch_bounds__(256) void mfma_gemm(
    const unsigned short* __restrict__ A, const unsigned short* __restrict__ WT,
    const float* __restrict__ bias, const float* __restrict__ resid,
    void* __restrict__ outp, int M, int N, int K,
    int rowmap, int act,
    unsigned short* __restrict__ vt_out,
    int vtNs, unsigned int vtMagic, int vtNsP, int vtColBase)
{
    constexpr int FI = BM / 32, FJ = BN / 32;
    constexpr int AL = BM / 64, BL = BN / 64;
    constexpr int W = SUB * (AL + BL);        // loads per K-superstep
    __shared__ __align__(16) unsigned short As[DEPTH][SUB * BM * 32];
    __shared__ __align__(16) unsigned short Bs[DEPTH][SUB * BN * 32];

    int tid = threadIdx.x;
    int m0 = blockIdx.y * BM, n0 = blockIdx.x * BN;
    int w = tid >> 6, l = tid & 63;
    int wm = (w >> 1) * (BM / 2), wn = (w & 1) * (BN / 2);
    int lr = l & 15, lg = l >> 4;

    int lrow = l >> 2;            // row within 16-row staging chunk
    int lcol = (l & 3) * 8;       // 16B chunk offset

    f32x4 zero = {0.f, 0.f, 0.f, 0.f};
    f32x4 acc[FI][FJ];
    #pragma unroll
    for (int i = 0; i < FI; ++i)
        #pragma unroll
        for (int j = 0; j < FJ; ++j) acc[i][j] = zero;

#define STAGE(buf, kk) do { \
    _Pragma("unroll") \
    for (int p = 0; p < SUB; ++p) { \
        _Pragma("unroll") \
        for (int q = 0; q < AL; ++q) { \
            int rb = (w * AL + q) * 16; \
            GLOAD_LDS16(A + (size_t)(m0 + rb + lrow) * K + (kk) + p * 32 + lcol, \
                        &As[buf][p * BM * 32 + rb * 32]); \
        } \
        _Pragma("unroll") \
        for (int q = 0; q < BL; ++q) { \
            int rb = (w * BL + q) * 16; \
            GLOAD_LDS16(WT + (size_t)(n0 + rb + lrow) * K + (kk) + p * 32 + lcol, \
                        &Bs[buf][p * BN * 32 + rb * 32]); \
        } \
    } \
} while (0)

    int nk = K / (32 * SUB);
    #pragma unroll
    for (int d = 0; d < DEPTH; ++d)
        STAGE(d, d * 32 * SUB);            // nk >= DEPTH for all our shapes
    int cur = 0;
    for (int s = 0; s < nk; ++s) {
        if (DEPTH >= 3 && s + 2 < nk) {
            // 2 tiles in flight beyond cur
            if constexpr (W == 2)
                asm volatile("s_waitcnt vmcnt(4)" ::: "memory");
            else if constexpr (W == 3)
                asm volatile("s_waitcnt vmcnt(6)" ::: "memory");
            else
                asm volatile("s_waitcnt vmcnt(8)" ::: "memory");
        } else if (s + 1 < nk) {
            if constexpr (W == 2)
                asm volatile("s_waitcnt vmcnt(2)" ::: "memory");
            else if constexpr (W == 3)
                asm volatile("s_waitcnt vmcnt(3)" ::: "memory");
            else
                asm volatile("s_waitcnt vmcnt(4)" ::: "memory");
        } else {
            asm volatile("s_waitcnt vmcnt(0)" ::: "memory");
        }
        __builtin_amdgcn_s_barrier();     // buf[cur] staged for all waves

        bf16x8 af[SUB][FI], bfr[SUB][FJ];
        #pragma unroll
        for (int p = 0; p < SUB; ++p) {
            #pragma unroll
            for (int i = 0; i < FI; ++i)
                af[p][i] = *(const bf16x8*)
                    &As[cur][p * BM * 32 + (wm + i * 16 + lr) * 32 + lg * 8];
            #pragma unroll
            for (int j = 0; j < FJ; ++j)
                bfr[p][j] = *(const bf16x8*)
                    &Bs[cur][p * BN * 32 + (wn + j * 16 + lr) * 32 + lg * 8];
        }
        asm volatile("s_waitcnt lgkmcnt(0)" ::: "memory");
        __builtin_amdgcn_sched_barrier(0);
        __builtin_amdgcn_s_barrier();     // all waves done reading buf[cur]
        if (s + DEPTH < nk) STAGE(cur, (s + DEPTH) * 32 * SUB);

        #pragma unroll
        for (int p = 0; p < SUB; ++p)
            #pragma unroll
            for (int i = 0; i < FI; ++i)
                #pragma unroll
                for (int j = 0; j < FJ; ++j)
                    acc[i][j] = __builtin_amdgcn_mfma_f32_16x16x32_bf16(
                        af[p][i], bfr[p][j], acc[i][j], 0, 0, 0);

        cur = (cur + 1 == DEPTH) ? 0 : cur + 1;
    }
#undef STAGE

    int rowW = vt_out ? vtColBase : N;
    // D layout: col = lane&15, row = (lane>>4)*4 + reg.
    #pragma unroll
    for (int i = 0; i < FI; ++i) {
        #pragma unroll
        for (int r = 0; r < 4; ++r) {
            int row = m0 + wm + i * 16 + lg * 4 + r;
            if (row >= M) continue;
            int orow = rowmap ? (row + 1 + row / 3136) : row;
            #pragma unroll
            for (int j = 0; j < FJ; ++j) {
                int col = n0 + wn + j * 16 + lr;
                if (col >= N) continue;
                float v = acc[i][j][r] + bias[col];
                if (act) v = gelu_f(v);
                if (resid) v += resid[(size_t)orow * N + col];
                if (vt_out && col >= vtColBase) {
                    unsigned int bb = (unsigned int)(((unsigned long long)(unsigned int)row * vtMagic) >> 32);
                    int nn = row - (int)bb * vtNs;
                    vt_out[((size_t)bb * 512 + (col - vtColBase)) * vtNsP + nn] = f2bf(v);
                } else if (OUT_BF16) {
                    ((unsigned short*)outp)[(size_t)orow * rowW + col] = f2bf(v);
                } else {
                    ((float*)outp)[(size_t)orow * rowW + col] = v;
                }
            }
        }
    }
}

// ---------------------------------------------------------------------------
// MFMA flash attention, bf16, 8-wave key-split, tail tile peeled.
// Softmax exps use raw v_exp_f32 (no libm wrapper).
// qt != 0: 1-D grid, XCD-clustered decode (K/V L2-resident; FETCH 9.5MB).
// ---------------------------------------------------------------------------
__global__ __launch_bounds__(512) void attn_mfma8(
    const unsigned short* __restrict__ qk, const unsigned short* __restrict__ vT,
    unsigned short* __restrict__ o, int Ns, int NsP, int qt)
{
    __shared__ __align__(16) unsigned short lds[4 * 4096];   // K p0|K p1|V p0|V p1

    int tid = threadIdx.x;
    int bx, h, b;
    if (qt) {
        int flat = blockIdx.x;
        int xcd = flat & 7, k = flat >> 3;
        int sel = (k >= qt) ? 1 : 0;
        int hb = xcd * 2 + sel;
        h = hb >> 1; b = hb & 1;
        bx = k - sel * qt;
    } else {
        bx = blockIdx.x; h = blockIdx.y; b = blockIdx.z;
    }
    int mb = b * Ns;
    int l = tid & 63, w = tid >> 6;
    int qg = w & 3, kp = w >> 2;
    int g = l >> 4, c16 = l & 15;

    int qrow = bx * 64 + qg * 16 + c16;
    int qr = (qrow < Ns ? qrow : Ns - 1) + mb;
    const unsigned short* qp = qk + (size_t)qr * 1024 + h * 64;
    bf16x8 bQ0 = *(const bf16x8*)(qp + g * 8);
    bf16x8 bQ1 = *(const bf16x8*)(qp + 32 + g * 8);

    f32x4 zero = {0.f, 0.f, 0.f, 0.f};
    f32x4 Oacc[4] = {zero, zero, zero, zero};
    float mrun = -1e30f, lrun = 0.f;      // per-lane partial sum

    // staging: row r0 = tid>>3 (0..63), chunk ch = tid&7; XOR-swizzled dest.
    int r0 = tid >> 3, ch = tid & 7;
    int kd = r0 * 64 + ((ch ^ ((r0 & 7) ^ (r0 >> 3))) * 8);
    const unsigned short* kbase = qk + (size_t)mb * 1024 + 512 + h * 64 + ch * 8;
    const unsigned short* vbase = vT + ((size_t)b * 512 + h * 64 + r0) * NsP + ch * 8;

    unsigned short* Kp = lds + kp * 4096;
    unsigned short* Vp = lds + 8192 + kp * 4096;

    // XOR bases for fragment reads.
    int sc = (c16 & 7) ^ (c16 >> 3);
    int k0 = c16 * 64 + ((g ^ sc) * 8);
    int v0 = c16 * 64 + (((g >> 1) ^ sc) * 8) + (g & 1) * 4;

    const float SCL = 0.125f * 1.4426950408889634f;  // scale * log2(e)
    int nt = (Ns + 127) >> 7;                        // total 128-key tiles
    int ntf = (Ns >= 128) ? ((Ns - 128) >> 7) + 1 : 0; // tiles full for BOTH parities

    u32x4 kv0, kv1, vv0, vv1;
#define LOADT(kt) do { \
    int kr0 = (kt) * 128 + r0;      if (kr0 >= Ns) kr0 = Ns - 1; \
    int kr1 = (kt) * 128 + 64 + r0; if (kr1 >= Ns) kr1 = Ns - 1; \
    kv0 = *(const u32x4*)(kbase + (size_t)kr0 * 1024); \
    kv1 = *(const u32x4*)(kbase + (size_t)kr1 * 1024); \
    vv0 = *(const u32x4*)(vbase + (kt) * 128); \
    vv1 = *(const u32x4*)(vbase + (kt) * 128 + 64); \
} while (0)
#define STORET() do { \
    *(u32x4*)&lds[kd] = kv0; \
    *(u32x4*)&lds[4096 + kd] = kv1; \
    *(u32x4*)&lds[8192 + kd] = vv0; \
    *(u32x4*)&lds[12288 + kd] = vv1; \
} while (0)

// Tile body. MASKED: apply validity masking for the ragged tail tile.
#define TILE_BODY(kt, MASKED) do { \
    /* S^T = K . Q^T (4 key-frags x 2 k-chunks) */ \
    f32x4 st[4]; \
    __builtin_amdgcn_s_setprio(1); \
    _Pragma("unroll") \
    for (int f = 0; f < 4; ++f) { \
        bf16x8 a0 = *(const bf16x8*)&Kp[k0 ^ (1040 * f)]; \
        bf16x8 a1 = *(const bf16x8*)&Kp[(k0 ^ (1040 * f)) ^ 32]; \
        f32x4 a = zero; \
        a = __builtin_amdgcn_mfma_f32_16x16x32_bf16(a0, bQ0, a, 0, 0, 0); \
        a = __builtin_amdgcn_mfma_f32_16x16x32_bf16(a1, bQ1, a, 0, 0, 0); \
        st[f] = a; \
    } \
    __builtin_amdgcn_s_setprio(0); \
    float sv[16]; \
    _Pragma("unroll") \
    for (int f = 0; f < 4; ++f) \
        _Pragma("unroll") \
        for (int r = 0; r < 4; ++r) sv[4 * f + r] = st[f][r]; \
    if (MASKED) { \
        int valid = Ns - (kt) * 128 - kp * 64; \
        _Pragma("unroll") \
        for (int f = 0; f < 4; ++f) \
            _Pragma("unroll") \
            for (int r = 0; r < 4; ++r) \
                if (16 * f + 4 * g + r >= valid) sv[4 * f + r] = -1e30f; \
    } \
    float mloc = sv[0]; \
    _Pragma("unroll") \
    for (int e = 1; e + 1 < 16; e += 2) \
        mloc = fmaxf(fmaxf(mloc, sv[e]), sv[e + 1]); \
    mloc = fmaxf(mloc, sv[15]); \
    if (!__all(mloc - mrun <= 64.f)) { \
        mloc = fmaxf(mloc, __shfl_xor(mloc, 16)); \
        mloc = fmaxf(mloc, __shfl_xor(mloc, 32)); \
        float mnew = fmaxf(mrun, mloc); \
        float scx = fexp2((mrun - mnew) * SCL); \
        lrun *= scx; \
        _Pragma("unroll") \
        for (int j = 0; j < 4; ++j) { \
            Oacc[j][0] *= scx; Oacc[j][1] *= scx; \
            Oacc[j][2] *= scx; Oacc[j][3] *= scx; \
        } \
        mrun = mnew; \
    } \
    float nl = mrun * SCL; \
    _Pragma("unroll") \
    for (int e = 0; e < 16; ++e) { \
        sv[e] = fexp2(fmaf(sv[e], SCL, -nl)); \
        lrun += sv[e]; \
    } \
    union { unsigned int u[4]; bf16x8 v; } plo, phi; \
    _Pragma("unroll") \
    for (int wi = 0; wi < 4; ++wi) { \
        asm("v_cvt_pk_bf16_f32 %0, %1, %2" \
            : "=v"(plo.u[wi]) : "v"(sv[2 * wi]), "v"(sv[2 * wi + 1])); \
        asm("v_cvt_pk_bf16_f32 %0, %1, %2" \
            : "=v"(phi.u[wi]) : "v"(sv[8 + 2 * wi]), "v"(sv[8 + 2 * wi + 1])); \
    } \
    __builtin_amdgcn_s_setprio(1); \
    _Pragma("unroll") \
    for (int j = 0; j < 4; ++j) { \
        int vb = v0 ^ (1040 * j); \
        bf16x4_t t0 = *(const bf16x4_t*)&Vp[vb]; \
        bf16x4_t t1 = *(const bf16x4_t*)&Vp[vb ^ 16]; \
        bf16x4_t t2 = *(const bf16x4_t*)&Vp[vb ^ 32]; \
        bf16x4_t t3 = *(const bf16x4_t*)&Vp[vb ^ 48]; \
        bf16x8 aVlo = __builtin_shufflevector(t0, t1, 0, 1, 2, 3, 4, 5, 6, 7); \
        bf16x8 aVhi = __builtin_shufflevector(t2, t3, 0, 1, 2, 3, 4, 5, 6, 7); \
        Oacc[j] = __builtin_amdgcn_mfma_f32_16x16x32_bf16(aVlo, plo.v, Oacc[j], 0, 0, 0); \
        Oacc[j] = __builtin_amdgcn_mfma_f32_16x16x32_bf16(aVhi, phi.v, Oacc[j], 0, 0, 0); \
    } \
    __builtin_amdgcn_s_setprio(0); \
} while (0)

    LOADT(0);
    for (int kt = 0; kt < ntf; ++kt) {       // full tiles: no masking
        __syncthreads();                     // prev tile reads done
        STORET();
        __syncthreads();                     // staging visible
        if (kt + 1 < nt) LOADT(kt + 1);      // issue next tile loads
        TILE_BODY(kt, 0);
    }
    for (int kt = ntf; kt < nt; ++kt) {      // ragged tail tile(s)
        __syncthreads();
        STORET();
        __syncthreads();
        if (kt + 1 < nt) LOADT(kt + 1);
        TILE_BODY(kt, 1);
    }
#undef TILE_BODY
#undef LOADT
#undef STORET

    // ---- exact merge of the two key-parity partials ----
    __syncthreads();                         // all compute done; LDS free
    float* xch = (float*)&lds[0];            // (qg*64+l)*20 floats, 20KB
    float* slot = xch + (size_t)(qg * 64 + l) * 20;
    if (kp == 1) {
        #pragma unroll
        for (int j = 0; j < 4; ++j)
            *(f32x4*)(slot + 4 * j) = Oacc[j];
        slot[16] = mrun;
        slot[17] = lrun;
    }
    __syncthreads();
    if (kp == 0) {
        float m1 = slot[16], l1 = slot[17];
        float mm = fmaxf(mrun, m1);
        float s0 = fexp2((mrun - mm) * SCL);
        float s1 = fexp2((m1 - mm) * SCL);
        lrun = lrun * s0 + l1 * s1;
        #pragma unroll
        for (int j = 0; j < 4; ++j) {
            f32x4 o1 = *(const f32x4*)(slot + 4 * j);
            Oacc[j][0] = Oacc[j][0] * s0 + o1[0] * s1;
            Oacc[j][1] = Oacc[j][1] * s0 + o1[1] * s1;
            Oacc[j][2] = Oacc[j][2] * s0 + o1[2] * s1;
            Oacc[j][3] = Oacc[j][3] * s0 + o1[3] * s1;
        }
        lrun += __shfl_xor(lrun, 16);
        lrun += __shfl_xor(lrun, 32);
        if (qrow < Ns) {
            float inv = 1.f / lrun;
            unsigned short* op = o + (size_t)(mb + qrow) * 512 + h * 64;
            #pragma unroll
            for (int j = 0; j < 4; ++j) {
                unsigned int u0, u1;
                asm("v_cvt_pk_bf16_f32 %0, %1, %2"
                    : "=v"(u0) : "v"(Oacc[j][0] * inv), "v"(Oacc[j][1] * inv));
                asm("v_cvt_pk_bf16_f32 %0, %1, %2"
                    : "=v"(u1) : "v"(Oacc[j][2] * inv), "v"(Oacc[j][3] * inv));
                uint2 stv; stv.x = u0; stv.y = u1;
                *(uint2*)(op + 16 * j + 4 * g) = stv;
            }
        }
    }
}

// ---------------------------------------------------------------------------
extern "C" void kernel_launch(void* const* d_in, const int* in_sizes, int n_in,
                              void* d_out, int out_size, void* d_ws, size_t ws_size,
                              hipStream_t stream)
{
    const float* x       = (const float*)d_in[0];
    const float* ln1_g   = (const float*)d_in[2];
    const float* ln1_b   = (const float*)d_in[3];
    const float* ln2_g   = (const float*)d_in[4];
    const float* ln2_b   = (const float*)d_in[5];
    const float* ln3_g   = (const float*)d_in[6];
    const float* ln3_b   = (const float*)d_in[7];
    const float* g_qkv_w = (const float*)d_in[8];
    const float* g_qkv_b = (const float*)d_in[9];
    const float* g_proj_w= (const float*)d_in[10];
    const float* g_proj_b= (const float*)d_in[11];
    const float* l_qkv_w = (const float*)d_in[12];
    const float* l_qkv_b = (const float*)d_in[13];
    const float* l_proj_w= (const float*)d_in[14];
    const float* l_proj_b= (const float*)d_in[15];
    const float* mlp_w1  = (const float*)d_in[16];
    const float* mlp_b1  = (const float*)d_in[17];
    const float* mlp_w2  = (const float*)d_in[18];
    const float* mlp_b2  = (const float*)d_in[19];

    float* out = (float*)d_out;

    // ws layout (ushort units)
    unsigned short* buf_a = (unsigned short*)d_ws;            // [6274][512] ln/attn bf16
    unsigned short* buf_b = buf_a + (size_t)6274 * 512;       // [6274][2048] qk / hidden
    unsigned short* vTb   = buf_b + (size_t)6274 * 2048;      // vT
    unsigned short* wbf   = vTb + (size_t)3276800 + 64;
    unsigned short* g_qkv_t  = wbf;                           // [1536][512]
    unsigned short* g_proj_t = g_qkv_t + 1536 * 512;          // [512][512]
    unsigned short* l_qkv_t  = g_proj_t + 512 * 512;          // [1536][512]
    unsigned short* l_proj_t = l_qkv_t + 1536 * 512;          // [512][512]
    unsigned short* w1_t     = l_proj_t + 512 * 512;          // [2048][512]
    unsigned short* w2_t     = w1_t + (size_t)2048 * 512;     // [512][2048]

    unsigned int M3137 = (unsigned int)((0x100000000ULL + 3136) / 3137);
    unsigned int M196  = (unsigned int)((0x100000000ULL + 195) / 196);

    TransArgs ta;
    ta.src[0] = g_qkv_w;  ta.dst[0] = g_qkv_t;  ta.N[0] = 1536; ta.K[0] = 512;  ta.off[0] = 0;
    ta.src[1] = g_proj_w; ta.dst[1] = g_proj_t; ta.N[1] = 512;  ta.K[1] = 512;  ta.off[1] = 768;
    ta.src[2] = l_qkv_w;  ta.dst[2] = l_qkv_t;  ta.N[2] = 1536; ta.K[2] = 512;  ta.off[2] = 1024;
    ta.src[3] = l_proj_w; ta.dst[3] = l_proj_t; ta.N[3] = 512;  ta.K[3] = 512;  ta.off[3] = 1792;
    ta.src[4] = mlp_w1;   ta.dst[4] = w1_t;     ta.N[4] = 2048; ta.K[4] = 512;  ta.off[4] = 2048;
    ta.src[5] = mlp_w2;   ta.dst[5] = w2_t;     ta.N[5] = 512;  ta.K[5] = 2048; ta.off[5] = 3072;
    transpose_all<<<4096, 256, 0, stream>>>(ta);

    // 1) ln1 = LN(x) -> bf16
    ln_kernel<<<1569, 256, 0, stream>>>(x, ln1_g, ln1_b, buf_a, 0, 6274);
    // 2) merged qkv_g: cols<1024 -> qk [6274][1024], cols>=1024 -> vT
    mfma_gemm<64,64,1,3,1><<<dim3(24, 99), 256, 0, stream>>>(
        buf_a, g_qkv_t, g_qkv_b, nullptr, buf_b, 6274, 1536, 512, 0, 0,
        vTb, 3137, M3137, 3144, 1024);
    // 3) global attention (8-wave key-split, XCD-clustered KV)
    attn_mfma8<<<dim3(800), 512, 0, stream>>>(buf_b, vTb, buf_a, 3137, 3144, 50);
    // 4) x1 = x + attn @ g_proj
    mfma_gemm<64,64,1,3,0><<<dim3(8, 99), 256, 0, stream>>>(
        buf_a, g_proj_t, g_proj_b, x, out, 6274, 512, 512, 0, 0,
        nullptr, 0, 0u, 0, 0);
    // 5) ln2 over patch rows -> bf16
    ln_kernel<<<1568, 256, 0, stream>>>(out, ln2_g, ln2_b, buf_a, 1, 6272);
    // 6) merged qkv_l
    mfma_gemm<64,64,1,3,1><<<dim3(24, 98), 256, 0, stream>>>(
        buf_a, l_qkv_t, l_qkv_b, nullptr, buf_b, 6272, 1536, 512, 0, 0,
        vTb, 196, M196, 200, 1024);
    // 7) local attention (32 sub-batches of 196)
    attn_mfma8<<<dim3(4, 8, 32), 512, 0, stream>>>(buf_b, vTb, buf_a, 196, 200, 0);
    // 8) patches += local @ l_proj  (rowmap)
    mfma_gemm<64,64,1,3,0><<<dim3(8, 98), 256, 0, stream>>>(
        buf_a, l_proj_t, l_proj_b, out, out, 6272, 512, 512, 1, 0,
        nullptr, 0, 0u, 0, 0);
    // 9) ln3 -> bf16
    ln_kernel<<<1569, 256, 0, stream>>>(out, ln3_g, ln3_b, buf_a, 0, 6274);
    // 10) hidden = gelu(ln3 @ w1 + b1) -> bf16
    mfma_gemm<64,64,1,3,1><<<dim3(32, 99), 256, 0, stream>>>(
        buf_a, w1_t, mlp_b1, nullptr, buf_b, 6274, 2048, 512, 0, 1,
        nullptr, 0, 0u, 0, 0);
    // 11) out = x2 + hidden @ w2 + b2
    mfma_gemm<64,64,1,3,0><<<dim3(8, 99), 256, 0, stream>>>(
        buf_b, w2_t, mlp_b2, out, out, 6274, 512, 2048, 0, 0,
        nullptr, 0, 0u, 0, 0);
}

// Round 20
// 313.898 us; speedup vs baseline: 1.0357x; 1.0357x over previous
//
#include <hip/hip_runtime.h>
#include <math.h>

typedef __attribute__((ext_vector_type(8))) short bf16x8;
typedef __attribute__((ext_vector_type(4))) short bf16x4_t;
typedef __attribute__((ext_vector_type(4))) float f32x4;
typedef __attribute__((ext_vector_type(4))) unsigned int u32x4;

typedef const __attribute__((address_space(1))) unsigned int glb_u32;
typedef __attribute__((address_space(3))) unsigned int lds_u32;
#define GLOAD_LDS16(g, l) __builtin_amdgcn_global_load_lds( \
    (glb_u32*)(const void*)(g), (lds_u32*)(void*)(l), 16, 0, 0)

static __device__ __forceinline__ float4 ld4(const float* p) {
    return *reinterpret_cast<const float4*>(p);
}
static __device__ __forceinline__ unsigned short f2bf(float f) {
    unsigned int u = __float_as_uint(f);
    u += 0x7fffu + ((u >> 16) & 1u);
    return (unsigned short)(u >> 16);
}
// Raw v_exp_f32 (2^x), no libm conformance wrapper (R17: -18% on attn).
static __device__ __forceinline__ float fexp2(float x) {
    return __builtin_amdgcn_exp2f(x);
}
// tanh-form GELU via exp2 + rcp: gelu(x) ~= x * t/(t+1), t = 2^(x*(a*x^2+b)).
static __device__ __forceinline__ float gelu_f(float v) {
    float t = fexp2(v * fmaf(v * v, 0.1029430f, 2.3022172f));
    return v - v * __builtin_amdgcn_rcpf(t + 1.f);
}

// ---------------------------------------------------------------------------
// LayerNorm: 4 rows per block (4 waves), bf16 output.
// mode=1: in_row = r + 1 + r/3136 (patch rows of (2,3137,512)).
// ---------------------------------------------------------------------------
__global__ __launch_bounds__(256) void ln_kernel(
    const float* __restrict__ in, const float* __restrict__ g,
    const float* __restrict__ bta, unsigned short* __restrict__ out,
    int mode, int nrows)
{
    int r = blockIdx.x * 4 + (threadIdx.x >> 6);
    if (r >= nrows) return;
    int lane = threadIdx.x & 63;
    int in_r = mode ? (r + 1 + r / 3136) : r;
    const float* xp = in + (size_t)in_r * 512 + lane * 8;
    float4 v0 = ld4(xp), v1 = ld4(xp + 4);
    float s  = v0.x + v0.y + v0.z + v0.w + v1.x + v1.y + v1.z + v1.w;
    float sq = v0.x*v0.x + v0.y*v0.y + v0.z*v0.z + v0.w*v0.w
             + v1.x*v1.x + v1.y*v1.y + v1.z*v1.z + v1.w*v1.w;
    #pragma unroll
    for (int off = 32; off; off >>= 1) {
        s  += __shfl_xor(s, off);
        sq += __shfl_xor(sq, off);
    }
    float mean = s * (1.f / 512.f);
    float var  = fmaxf(sq * (1.f / 512.f) - mean * mean, 0.f);
    float rstd = rsqrtf(var + 1e-5f);
    float4 g0 = ld4(g + lane * 8),   g1 = ld4(g + lane * 8 + 4);
    float4 b0 = ld4(bta + lane * 8), b1 = ld4(bta + lane * 8 + 4);
    float o0 = (v0.x - mean) * rstd * g0.x + b0.x;
    float o1 = (v0.y - mean) * rstd * g0.y + b0.y;
    float o2 = (v0.z - mean) * rstd * g0.z + b0.z;
    float o3 = (v0.w - mean) * rstd * g0.w + b0.w;
    float o4 = (v1.x - mean) * rstd * g1.x + b1.x;
    float o5 = (v1.y - mean) * rstd * g1.y + b1.y;
    float o6 = (v1.z - mean) * rstd * g1.z + b1.z;
    float o7 = (v1.w - mean) * rstd * g1.w + b1.w;
    u32x4 pk;
    pk[0] = (unsigned int)f2bf(o0) | ((unsigned int)f2bf(o1) << 16);
    pk[1] = (unsigned int)f2bf(o2) | ((unsigned int)f2bf(o3) << 16);
    pk[2] = (unsigned int)f2bf(o4) | ((unsigned int)f2bf(o5) << 16);
    pk[3] = (unsigned int)f2bf(o6) | ((unsigned int)f2bf(o7) << 16);
    *(u32x4*)(out + (size_t)r * 512 + lane * 8) = pk;
}

// ---------------------------------------------------------------------------
// All six weight transposes in one launch. W[K][N] -> WT[N][K] bf16.
// ---------------------------------------------------------------------------
struct TransArgs {
    const float* src[6];
    unsigned short* dst[6];
    int N[6], K[6], off[6];
};

__global__ __launch_bounds__(256) void transpose_all(TransArgs a)
{
    __shared__ unsigned short tile[32][34];
    int t = blockIdx.x;
    int i = 0;
    #pragma unroll
    for (int j = 1; j < 6; ++j) if (t >= a.off[j]) i = j;
    int rel = t - a.off[i];
    int tx_n = a.N[i] >> 5;
    int bx = (rel % tx_n) * 32, by = (rel / tx_n) * 32;
    const float* W = a.src[i];
    unsigned short* WT = a.dst[i];
    int K = a.K[i], N = a.N[i];
    int tx = threadIdx.x & 31, ty = threadIdx.x >> 5;
    #pragma unroll
    for (int r = 0; r < 32; r += 8)
        tile[ty + r][tx] = f2bf(W[(size_t)(by + ty + r) * N + bx + tx]);
    __syncthreads();
    #pragma unroll
    for (int r = 0; r < 32; r += 8)
        WT[(size_t)(bx + ty + r) * K + by + tx] = tile[tx][ty + r];
}

// ---------------------------------------------------------------------------
// MFMA bf16 GEMM, depth-2 pipelined global_load_lds (counted vmcnt, raw
// barriers). SUB = K-substeps per barrier pair. Grid: x = N-tiles (fastest),
// y = M-tiles (A-panel L2 reuse). vt_out: cols >= vtColBase go to
// [b][col-vtColBase][token] layout (token stride vtNsP, b = row/vtNs).
// Ledger: DEPTH=3 (-), SUB=2 (0), L2-swap (0), block-count saturates ~1200.
// ---------------------------------------------------------------------------
template<int BM, int BN, int SUB, int OUT_BF16>
__global__ __launch_bounds__(256) void mfma_gemm(
    const unsigned short* __restrict__ A, const unsigned short* __restrict__ WT,
    const float* __restrict__ bias, const float* __restrict__ resid,
    void* __restrict__ outp, int M, int N, int K,
    int rowmap, int act,
    unsigned short* __restrict__ vt_out,
    int vtNs, unsigned int vtMagic, int vtNsP, int vtColBase)
{
    constexpr int FI = BM / 32, FJ = BN / 32;
    constexpr int AL = BM / 64, BL = BN / 64;
    constexpr int W = SUB * (AL + BL);        // loads per superstep
    __shared__ __align__(16) unsigned short As[2][SUB * BM * 32];
    __shared__ __align__(16) unsigned short Bs[2][SUB * BN * 32];

    int tid = threadIdx.x;
    int m0 = blockIdx.y * BM, n0 = blockIdx.x * BN;
    int w = tid >> 6, l = tid & 63;
    int wm = (w >> 1) * (BM / 2), wn = (w & 1) * (BN / 2);
    int lr = l & 15, lg = l >> 4;

    int lrow = l >> 2;            // row within 16-row staging chunk
    int lcol = (l & 3) * 8;       // 16B chunk offset

    f32x4 zero = {0.f, 0.f, 0.f, 0.f};
    f32x4 acc[FI][FJ];
    #pragma unroll
    for (int i = 0; i < FI; ++i)
        #pragma unroll
        for (int j = 0; j < FJ; ++j) acc[i][j] = zero;

#define STAGE(buf, kk) do { \
    _Pragma("unroll") \
    for (int p = 0; p < SUB; ++p) { \
        _Pragma("unroll") \
        for (int q = 0; q < AL; ++q) { \
            int rb = (w * AL + q) * 16; \
            GLOAD_LDS16(A + (size_t)(m0 + rb + lrow) * K + (kk) + p * 32 + lcol, \
                        &As[buf][p * BM * 32 + rb * 32]); \
        } \
        _Pragma("unroll") \
        for (int q = 0; q < BL; ++q) { \
            int rb = (w * BL + q) * 16; \
            GLOAD_LDS16(WT + (size_t)(n0 + rb + lrow) * K + (kk) + p * 32 + lcol, \
                        &Bs[buf][p * BN * 32 + rb * 32]); \
        } \
    } \
} while (0)

    int nk = K / (32 * SUB);
    STAGE(0, 0);
    STAGE(1, 32 * SUB);
    for (int s = 0; s < nk; ++s) {
        int cur = s & 1;
        if (s + 1 < nk) {
            if constexpr (W == 2)
                asm volatile("s_waitcnt vmcnt(2)" ::: "memory");
            else if constexpr (W == 3)
                asm volatile("s_waitcnt vmcnt(3)" ::: "memory");
            else if constexpr (W == 4)
                asm volatile("s_waitcnt vmcnt(4)" ::: "memory");
            else if constexpr (W == 6)
                asm volatile("s_waitcnt vmcnt(6)" ::: "memory");
            else
                asm volatile("s_waitcnt vmcnt(8)" ::: "memory");
        } else {
            asm volatile("s_waitcnt vmcnt(0)" ::: "memory");
        }
        __builtin_amdgcn_s_barrier();     // buf[cur] staged for all waves

        bf16x8 af[SUB][FI], bfr[SUB][FJ];
        #pragma unroll
        for (int p = 0; p < SUB; ++p) {
            #pragma unroll
            for (int i = 0; i < FI; ++i)
                af[p][i] = *(const bf16x8*)
                    &As[cur][p * BM * 32 + (wm + i * 16 + lr) * 32 + lg * 8];
            #pragma unroll
            for (int j = 0; j < FJ; ++j)
                bfr[p][j] = *(const bf16x8*)
                    &Bs[cur][p * BN * 32 + (wn + j * 16 + lr) * 32 + lg * 8];
        }
        asm volatile("s_waitcnt lgkmcnt(0)" ::: "memory");
        __builtin_amdgcn_sched_barrier(0);
        __builtin_amdgcn_s_barrier();     // all waves done reading buf[cur]
        if (s + 2 < nk) STAGE(cur, (s + 2) * 32 * SUB);

        #pragma unroll
        for (int p = 0; p < SUB; ++p)
            #pragma unroll
            for (int i = 0; i < FI; ++i)
                #pragma unroll
                for (int j = 0; j < FJ; ++j)
                    acc[i][j] = __builtin_amdgcn_mfma_f32_16x16x32_bf16(
                        af[p][i], bfr[p][j], acc[i][j], 0, 0, 0);
    }
#undef STAGE

    int rowW = vt_out ? vtColBase : N;
    // D layout: col = lane&15, row = (lane>>4)*4 + reg.
    #pragma unroll
    for (int i = 0; i < FI; ++i) {
        #pragma unroll
        for (int r = 0; r < 4; ++r) {
            int row = m0 + wm + i * 16 + lg * 4 + r;
            if (row >= M) continue;
            int orow = rowmap ? (row + 1 + row / 3136) : row;
            #pragma unroll
            for (int j = 0; j < FJ; ++j) {
                int col = n0 + wn + j * 16 + lr;
                if (col >= N) continue;
                float v = acc[i][j][r] + bias[col];
                if (act) v = gelu_f(v);
                if (resid) v += resid[(size_t)orow * N + col];
                if (vt_out && col >= vtColBase) {
                    unsigned int bb = (unsigned int)(((unsigned long long)(unsigned int)row * vtMagic) >> 32);
                    int nn = row - (int)bb * vtNs;
                    vt_out[((size_t)bb * 512 + (col - vtColBase)) * vtNsP + nn] = f2bf(v);
                } else if (OUT_BF16) {
                    ((unsigned short*)outp)[(size_t)orow * rowW + col] = f2bf(v);
                } else {
                    ((float*)outp)[(size_t)orow * rowW + col] = v;
                }
            }
        }
    }
}

// ---------------------------------------------------------------------------
// MFMA flash attention, bf16, 8-wave key-split, tail tile peeled.
// Softmax exps use raw v_exp_f32 (no libm wrapper).
// qt != 0: 1-D grid, XCD-clustered decode (K/V L2-resident; FETCH 9.5MB).
// ---------------------------------------------------------------------------
__global__ __launch_bounds__(512) void attn_mfma8(
    const unsigned short* __restrict__ qk, const unsigned short* __restrict__ vT,
    unsigned short* __restrict__ o, int Ns, int NsP, int qt)
{
    __shared__ __align__(16) unsigned short lds[4 * 4096];   // K p0|K p1|V p0|V p1

    int tid = threadIdx.x;
    int bx, h, b;
    if (qt) {
        int flat = blockIdx.x;
        int xcd = flat & 7, k = flat >> 3;
        int sel = (k >= qt) ? 1 : 0;
        int hb = xcd * 2 + sel;
        h = hb >> 1; b = hb & 1;
        bx = k - sel * qt;
    } else {
        bx = blockIdx.x; h = blockIdx.y; b = blockIdx.z;
    }
    int mb = b * Ns;
    int l = tid & 63, w = tid >> 6;
    int qg = w & 3, kp = w >> 2;
    int g = l >> 4, c16 = l & 15;

    int qrow = bx * 64 + qg * 16 + c16;
    int qr = (qrow < Ns ? qrow : Ns - 1) + mb;
    const unsigned short* qp = qk + (size_t)qr * 1024 + h * 64;
    bf16x8 bQ0 = *(const bf16x8*)(qp + g * 8);
    bf16x8 bQ1 = *(const bf16x8*)(qp + 32 + g * 8);

    f32x4 zero = {0.f, 0.f, 0.f, 0.f};
    f32x4 Oacc[4] = {zero, zero, zero, zero};
    float mrun = -1e30f, lrun = 0.f;      // per-lane partial sum

    // staging: row r0 = tid>>3 (0..63), chunk ch = tid&7; XOR-swizzled dest.
    int r0 = tid >> 3, ch = tid & 7;
    int kd = r0 * 64 + ((ch ^ ((r0 & 7) ^ (r0 >> 3))) * 8);
    const unsigned short* kbase = qk + (size_t)mb * 1024 + 512 + h * 64 + ch * 8;
    const unsigned short* vbase = vT + ((size_t)b * 512 + h * 64 + r0) * NsP + ch * 8;

    unsigned short* Kp = lds + kp * 4096;
    unsigned short* Vp = lds + 8192 + kp * 4096;

    // XOR bases for fragment reads.
    int sc = (c16 & 7) ^ (c16 >> 3);
    int k0 = c16 * 64 + ((g ^ sc) * 8);
    int v0 = c16 * 64 + (((g >> 1) ^ sc) * 8) + (g & 1) * 4;

    const float SCL = 0.125f * 1.4426950408889634f;  // scale * log2(e)
    int nt = (Ns + 127) >> 7;                        // total 128-key tiles
    int ntf = (Ns >= 128) ? ((Ns - 128) >> 7) + 1 : 0; // tiles full for BOTH parities

    u32x4 kv0, kv1, vv0, vv1;
#define LOADT(kt) do { \
    int kr0 = (kt) * 128 + r0;      if (kr0 >= Ns) kr0 = Ns - 1; \
    int kr1 = (kt) * 128 + 64 + r0; if (kr1 >= Ns) kr1 = Ns - 1; \
    kv0 = *(const u32x4*)(kbase + (size_t)kr0 * 1024); \
    kv1 = *(const u32x4*)(kbase + (size_t)kr1 * 1024); \
    vv0 = *(const u32x4*)(vbase + (kt) * 128); \
    vv1 = *(const u32x4*)(vbase + (kt) * 128 + 64); \
} while (0)
#define STORET() do { \
    *(u32x4*)&lds[kd] = kv0; \
    *(u32x4*)&lds[4096 + kd] = kv1; \
    *(u32x4*)&lds[8192 + kd] = vv0; \
    *(u32x4*)&lds[12288 + kd] = vv1; \
} while (0)

// Tile body. MASKED: apply validity masking for the ragged tail tile.
#define TILE_BODY(kt, MASKED) do { \
    /* S^T = K . Q^T (4 key-frags x 2 k-chunks) */ \
    f32x4 st[4]; \
    __builtin_amdgcn_s_setprio(1); \
    _Pragma("unroll") \
    for (int f = 0; f < 4; ++f) { \
        bf16x8 a0 = *(const bf16x8*)&Kp[k0 ^ (1040 * f)]; \
        bf16x8 a1 = *(const bf16x8*)&Kp[(k0 ^ (1040 * f)) ^ 32]; \
        f32x4 a = zero; \
        a = __builtin_amdgcn_mfma_f32_16x16x32_bf16(a0, bQ0, a, 0, 0, 0); \
        a = __builtin_amdgcn_mfma_f32_16x16x32_bf16(a1, bQ1, a, 0, 0, 0); \
        st[f] = a; \
    } \
    __builtin_amdgcn_s_setprio(0); \
    float sv[16]; \
    _Pragma("unroll") \
    for (int f = 0; f < 4; ++f) \
        _Pragma("unroll") \
        for (int r = 0; r < 4; ++r) sv[4 * f + r] = st[f][r]; \
    if (MASKED) { \
        int valid = Ns - (kt) * 128 - kp * 64; \
        _Pragma("unroll") \
        for (int f = 0; f < 4; ++f) \
            _Pragma("unroll") \
            for (int r = 0; r < 4; ++r) \
                if (16 * f + 4 * g + r >= valid) sv[4 * f + r] = -1e30f; \
    } \
    float mloc = sv[0]; \
    _Pragma("unroll") \
    for (int e = 1; e + 1 < 16; e += 2) \
        mloc = fmaxf(fmaxf(mloc, sv[e]), sv[e + 1]); \
    mloc = fmaxf(mloc, sv[15]); \
    if (!__all(mloc - mrun <= 64.f)) { \
        mloc = fmaxf(mloc, __shfl_xor(mloc, 16)); \
        mloc = fmaxf(mloc, __shfl_xor(mloc, 32)); \
        float mnew = fmaxf(mrun, mloc); \
        float scx = fexp2((mrun - mnew) * SCL); \
        lrun *= scx; \
        _Pragma("unroll") \
        for (int j = 0; j < 4; ++j) { \
            Oacc[j][0] *= scx; Oacc[j][1] *= scx; \
            Oacc[j][2] *= scx; Oacc[j][3] *= scx; \
        } \
        mrun = mnew; \
    } \
    float nl = mrun * SCL; \
    _Pragma("unroll") \
    for (int e = 0; e < 16; ++e) { \
        sv[e] = fexp2(fmaf(sv[e], SCL, -nl)); \
        lrun += sv[e]; \
    } \
    union { unsigned int u[4]; bf16x8 v; } plo, phi; \
    _Pragma("unroll") \
    for (int wi = 0; wi < 4; ++wi) { \
        asm("v_cvt_pk_bf16_f32 %0, %1, %2" \
            : "=v"(plo.u[wi]) : "v"(sv[2 * wi]), "v"(sv[2 * wi + 1])); \
        asm("v_cvt_pk_bf16_f32 %0, %1, %2" \
            : "=v"(phi.u[wi]) : "v"(sv[8 + 2 * wi]), "v"(sv[8 + 2 * wi + 1])); \
    } \
    __builtin_amdgcn_s_setprio(1); \
    _Pragma("unroll") \
    for (int j = 0; j < 4; ++j) { \
        int vb = v0 ^ (1040 * j); \
        bf16x4_t t0 = *(const bf16x4_t*)&Vp[vb]; \
        bf16x4_t t1 = *(const bf16x4_t*)&Vp[vb ^ 16]; \
        bf16x4_t t2 = *(const bf16x4_t*)&Vp[vb ^ 32]; \
        bf16x4_t t3 = *(const bf16x4_t*)&Vp[vb ^ 48]; \
        bf16x8 aVlo = __builtin_shufflevector(t0, t1, 0, 1, 2, 3, 4, 5, 6, 7); \
        bf16x8 aVhi = __builtin_shufflevector(t2, t3, 0, 1, 2, 3, 4, 5, 6, 7); \
        Oacc[j] = __builtin_amdgcn_mfma_f32_16x16x32_bf16(aVlo, plo.v, Oacc[j], 0, 0, 0); \
        Oacc[j] = __builtin_amdgcn_mfma_f32_16x16x32_bf16(aVhi, phi.v, Oacc[j], 0, 0, 0); \
    } \
    __builtin_amdgcn_s_setprio(0); \
} while (0)

    LOADT(0);
    for (int kt = 0; kt < ntf; ++kt) {       // full tiles: no masking
        __syncthreads();                     // prev tile reads done
        STORET();
        __syncthreads();                     // staging visible
        if (kt + 1 < nt) LOADT(kt + 1);      // issue next tile loads
        TILE_BODY(kt, 0);
    }
    for (int kt = ntf; kt < nt; ++kt) {      // ragged tail tile(s)
        __syncthreads();
        STORET();
        __syncthreads();
        if (kt + 1 < nt) LOADT(kt + 1);
        TILE_BODY(kt, 1);
    }
#undef TILE_BODY
#undef LOADT
#undef STORET

    // ---- exact merge of the two key-parity partials ----
    __syncthreads();                         // all compute done; LDS free
    float* xch = (float*)&lds[0];            // (qg*64+l)*20 floats, 20KB
    float* slot = xch + (size_t)(qg * 64 + l) * 20;
    if (kp == 1) {
        #pragma unroll
        for (int j = 0; j < 4; ++j)
            *(f32x4*)(slot + 4 * j) = Oacc[j];
        slot[16] = mrun;
        slot[17] = lrun;
    }
    __syncthreads();
    if (kp == 0) {
        float m1 = slot[16], l1 = slot[17];
        float mm = fmaxf(mrun, m1);
        float s0 = fexp2((mrun - mm) * SCL);
        float s1 = fexp2((m1 - mm) * SCL);
        lrun = lrun * s0 + l1 * s1;
        #pragma unroll
        for (int j = 0; j < 4; ++j) {
            f32x4 o1 = *(const f32x4*)(slot + 4 * j);
            Oacc[j][0] = Oacc[j][0] * s0 + o1[0] * s1;
            Oacc[j][1] = Oacc[j][1] * s0 + o1[1] * s1;
            Oacc[j][2] = Oacc[j][2] * s0 + o1[2] * s1;
            Oacc[j][3] = Oacc[j][3] * s0 + o1[3] * s1;
        }
        lrun += __shfl_xor(lrun, 16);
        lrun += __shfl_xor(lrun, 32);
        if (qrow < Ns) {
            float inv = 1.f / lrun;
            unsigned short* op = o + (size_t)(mb + qrow) * 512 + h * 64;
            #pragma unroll
            for (int j = 0; j < 4; ++j) {
                unsigned int u0, u1;
                asm("v_cvt_pk_bf16_f32 %0, %1, %2"
                    : "=v"(u0) : "v"(Oacc[j][0] * inv), "v"(Oacc[j][1] * inv));
                asm("v_cvt_pk_bf16_f32 %0, %1, %2"
                    : "=v"(u1) : "v"(Oacc[j][2] * inv), "v"(Oacc[j][3] * inv));
                uint2 stv; stv.x = u0; stv.y = u1;
                *(uint2*)(op + 16 * j + 4 * g) = stv;
            }
        }
    }
}

// ---------------------------------------------------------------------------
extern "C" void kernel_launch(void* const* d_in, const int* in_sizes, int n_in,
                              void* d_out, int out_size, void* d_ws, size_t ws_size,
                              hipStream_t stream)
{
    const float* x       = (const float*)d_in[0];
    const float* ln1_g   = (const float*)d_in[2];
    const float* ln1_b   = (const float*)d_in[3];
    const float* ln2_g   = (const float*)d_in[4];
    const float* ln2_b   = (const float*)d_in[5];
    const float* ln3_g   = (const float*)d_in[6];
    const float* ln3_b   = (const float*)d_in[7];
    const float* g_qkv_w = (const float*)d_in[8];
    const float* g_qkv_b = (const float*)d_in[9];
    const float* g_proj_w= (const float*)d_in[10];
    const float* g_proj_b= (const float*)d_in[11];
    const float* l_qkv_w = (const float*)d_in[12];
    const float* l_qkv_b = (const float*)d_in[13];
    const float* l_proj_w= (const float*)d_in[14];
    const float* l_proj_b= (const float*)d_in[15];
    const float* mlp_w1  = (const float*)d_in[16];
    const float* mlp_b1  = (const float*)d_in[17];
    const float* mlp_w2  = (const float*)d_in[18];
    const float* mlp_b2  = (const float*)d_in[19];

    float* out = (float*)d_out;

    // ws layout (ushort units)
    unsigned short* buf_a = (unsigned short*)d_ws;            // [6274][512] ln/attn bf16
    unsigned short* buf_b = buf_a + (size_t)6274 * 512;       // [6274][2048] qk / hidden
    unsigned short* vTb   = buf_b + (size_t)6274 * 2048;      // vT
    unsigned short* wbf   = vTb + (size_t)3276800 + 64;
    unsigned short* g_qkv_t  = wbf;                           // [1536][512]
    unsigned short* g_proj_t = g_qkv_t + 1536 * 512;          // [512][512]
    unsigned short* l_qkv_t  = g_proj_t + 512 * 512;          // [1536][512]
    unsigned short* l_proj_t = l_qkv_t + 1536 * 512;          // [512][512]
    unsigned short* w1_t     = l_proj_t + 512 * 512;          // [2048][512]
    unsigned short* w2_t     = w1_t + (size_t)2048 * 512;     // [512][2048]

    unsigned int M3137 = (unsigned int)((0x100000000ULL + 3136) / 3137);
    unsigned int M196  = (unsigned int)((0x100000000ULL + 195) / 196);

    TransArgs ta;
    ta.src[0] = g_qkv_w;  ta.dst[0] = g_qkv_t;  ta.N[0] = 1536; ta.K[0] = 512;  ta.off[0] = 0;
    ta.src[1] = g_proj_w; ta.dst[1] = g_proj_t; ta.N[1] = 512;  ta.K[1] = 512;  ta.off[1] = 768;
    ta.src[2] = l_qkv_w;  ta.dst[2] = l_qkv_t;  ta.N[2] = 1536; ta.K[2] = 512;  ta.off[2] = 1024;
    ta.src[3] = l_proj_w; ta.dst[3] = l_proj_t; ta.N[3] = 512;  ta.K[3] = 512;  ta.off[3] = 1792;
    ta.src[4] = mlp_w1;   ta.dst[4] = w1_t;     ta.N[4] = 2048; ta.K[4] = 512;  ta.off[4] = 2048;
    ta.src[5] = mlp_w2;   ta.dst[5] = w2_t;     ta.N[5] = 512;  ta.K[5] = 2048; ta.off[5] = 3072;
    transpose_all<<<4096, 256, 0, stream>>>(ta);

    // 1) ln1 = LN(x) -> bf16
    ln_kernel<<<1569, 256, 0, stream>>>(x, ln1_g, ln1_b, buf_a, 0, 6274);
    // 2) merged qkv_g: cols<1024 -> qk [6274][1024], cols>=1024 -> vT
    mfma_gemm<64,64,1,1><<<dim3(24, 99), 256, 0, stream>>>(
        buf_a, g_qkv_t, g_qkv_b, nullptr, buf_b, 6274, 1536, 512, 0, 0,
        vTb, 3137, M3137, 3144, 1024);
    // 3) global attention (8-wave key-split, XCD-clustered KV)
    attn_mfma8<<<dim3(800), 512, 0, stream>>>(buf_b, vTb, buf_a, 3137, 3144, 50);
    // 4) x1 = x + attn @ g_proj
    mfma_gemm<64,64,1,0><<<dim3(8, 99), 256, 0, stream>>>(
        buf_a, g_proj_t, g_proj_b, x, out, 6274, 512, 512, 0, 0,
        nullptr, 0, 0u, 0, 0);
    // 5) ln2 over patch rows -> bf16
    ln_kernel<<<1568, 256, 0, stream>>>(out, ln2_g, ln2_b, buf_a, 1, 6272);
    // 6) merged qkv_l
    mfma_gemm<64,64,1,1><<<dim3(24, 98), 256, 0, stream>>>(
        buf_a, l_qkv_t, l_qkv_b, nullptr, buf_b, 6272, 1536, 512, 0, 0,
        vTb, 196, M196, 200, 1024);
    // 7) local attention (32 sub-batches of 196)
    attn_mfma8<<<dim3(4, 8, 32), 512, 0, stream>>>(buf_b, vTb, buf_a, 196, 200, 0);
    // 8) patches += local @ l_proj  (rowmap)
    mfma_gemm<64,64,1,0><<<dim3(8, 98), 256, 0, stream>>>(
        buf_a, l_proj_t, l_proj_b, out, out, 6272, 512, 512, 1, 0,
        nullptr, 0, 0u, 0, 0);
    // 9) ln3 -> bf16
    ln_kernel<<<1569, 256, 0, stream>>>(out, ln3_g, ln3_b, buf_a, 0, 6274);
    // 10) hidden = gelu(ln3 @ w1 + b1) -> bf16
    mfma_gemm<64,64,1,1><<<dim3(32, 99), 256, 0, stream>>>(
        buf_a, w1_t, mlp_b1, nullptr, buf_b, 6274, 2048, 512, 0, 1,
        nullptr, 0, 0u, 0, 0);
    // 11) out = x2 + hidden @ w2 + b2
    mfma_gemm<64,64,1,0><<<dim3(8, 99), 256, 0, stream>>>(
        buf_b, w2_t, mlp_b2, out, out, 6274, 512, 2048, 0, 0,
        nullptr, 0, 0u, 0, 0);
}